// Round 8
// baseline (370.161 us; speedup 1.0000x reference)
//
#include <hip/hip_runtime.h>
#include <hip/hip_bf16.h>

#define N_NODES 50000
#define N_EDGES 800000
#define N_GRAPHS 512
#define EMB 64
#define HID 128

// bf16 helpers: RNE pack, shift-unpack (bf16->f32 is exact)
__device__ __forceinline__ unsigned f2bf(float f) {
    unsigned x = __float_as_uint(f);
    return (x + 0x7fffu + ((x >> 16) & 1u)) >> 16;
}
__device__ __forceinline__ unsigned packbf(float lo, float hi) {
    return f2bf(lo) | (f2bf(hi) << 16);
}
__device__ __forceinline__ float bf_lo(unsigned u) { return __uint_as_float(u << 16); }
__device__ __forceinline__ float bf_hi(unsigned u) { return __uint_as_float(u & 0xffff0000u); }

// ------------------- embed gather + degree histogram + bf16 mirror of h0
__global__ void k_embed_hist(const int* __restrict__ x, const float* __restrict__ emb,
                             const int* __restrict__ ei, float* __restrict__ h0,
                             uint2* __restrict__ h0b, int* __restrict__ deg) {
    int t = blockIdx.x * 256 + threadIdx.x;
    if (t >= N_EDGES) return;
    int n = t >> 4, c4 = t & 15;
    const float4* e4 = (const float4*)emb;
    float4 v = e4[(size_t)x[n] * 16 + c4];
    ((float4*)h0)[(size_t)n * 16 + c4] = v;
    uint2 b; b.x = packbf(v.x, v.y); b.y = packbf(v.z, v.w);
    h0b[(size_t)n * 16 + c4] = b;
    atomicAdd(&deg[ei[N_EDGES + t]], 1);
}

// ---------------------------------------------------------------- 3-phase scan
__global__ void k_scanA(const int* __restrict__ deg, int* __restrict__ rowptr,
                        int* __restrict__ bsums) {
    __shared__ int s[256];
    int t = threadIdx.x, i = blockIdx.x * 256 + t;
    int v = (i < N_NODES) ? deg[i] : 0;
    s[t] = v; __syncthreads();
    int xv = v;
    for (int off = 1; off < 256; off <<= 1) {
        int y = (t >= off) ? s[t - off] : 0;
        __syncthreads();
        xv += y; s[t] = xv;
        __syncthreads();
    }
    if (i < N_NODES) rowptr[i] = xv - v;
    if (t == 255) bsums[blockIdx.x] = xv;
}

__global__ void k_scanB(int* __restrict__ bsums, int nb) {
    __shared__ int s[256];
    int t = threadIdx.x;
    int v = (t < nb) ? bsums[t] : 0;
    s[t] = v; __syncthreads();
    int xv = v;
    for (int off = 1; off < 256; off <<= 1) {
        int y = (t >= off) ? s[t - off] : 0;
        __syncthreads();
        xv += y; s[t] = xv;
        __syncthreads();
    }
    if (t < nb) bsums[t] = xv - v;
}

__global__ void k_scanC(int* __restrict__ rowptr, int* __restrict__ wp,
                        const int* __restrict__ bsums) {
    int i = blockIdx.x * 256 + threadIdx.x;
    if (i < N_NODES) {
        int v = rowptr[i] + bsums[blockIdx.x];
        rowptr[i] = v;
        wp[i] = v;
    }
    if (i == 0) rowptr[N_NODES] = N_EDGES;
}

// ---------------------------------------------------------------- edge scatter
__global__ void k_scatter(const int* __restrict__ ei, int* __restrict__ wp,
                          int* __restrict__ nbr) {
    int e = blockIdx.x * 256 + threadIdx.x;
    if (e >= N_EDGES) return;
    int s = ei[e], d = ei[N_EDGES + e];
    int pos = atomicAdd(&wp[d], 1);
    nbr[pos] = s;
}

// ----------------------------------------------- bf16 agg device function
// gathers bf16 rows (F=128: 32 lanes x uint2 = 256B; F=64: 16 lanes x uint2),
// accumulates f32, writes f32 mean. 8-deep ILP.
template <int F>
__device__ __forceinline__ void agg_tile_bf(const uint2* __restrict__ hb,
                                            const int* __restrict__ rowptr,
                                            const int* __restrict__ nbr,
                                            float* __restrict__ mean,
                                            int aggIdx, int t) {
    int wl = t >> 6;
    int l = t & 63;
    float4* m4 = (float4*)mean;

    int n, c;
    if constexpr (F == 128) { n = aggIdx * 16 + wl * 2 + (l >> 5); c = l & 31; }
    else                    { n = aggIdx * 32 + wl * 4 + (l >> 4); c = l & 15; }
    if (n >= N_NODES) return;
    constexpr int CU2 = F / 4;        // uint2 per row

    int r0 = rowptr[n], r1 = rowptr[n + 1];
    float inv = 1.0f / (float)max(r1 - r0, 1);

    float4 a[8];
    #pragma unroll
    for (int u = 0; u < 8; ++u) a[u] = make_float4(0.f, 0.f, 0.f, 0.f);

    int i = r0;
    for (; i + 7 < r1; i += 8) {
        int s0 = nbr[i + 0], s1 = nbr[i + 1], s2 = nbr[i + 2], s3 = nbr[i + 3];
        int s4 = nbr[i + 4], s5 = nbr[i + 5], s6 = nbr[i + 6], s7 = nbr[i + 7];
        uint2 v0 = hb[(size_t)s0 * CU2 + c];
        uint2 v1 = hb[(size_t)s1 * CU2 + c];
        uint2 v2 = hb[(size_t)s2 * CU2 + c];
        uint2 v3 = hb[(size_t)s3 * CU2 + c];
        uint2 v4 = hb[(size_t)s4 * CU2 + c];
        uint2 v5 = hb[(size_t)s5 * CU2 + c];
        uint2 v6 = hb[(size_t)s6 * CU2 + c];
        uint2 v7 = hb[(size_t)s7 * CU2 + c];
        a[0].x += bf_lo(v0.x); a[0].y += bf_hi(v0.x); a[0].z += bf_lo(v0.y); a[0].w += bf_hi(v0.y);
        a[1].x += bf_lo(v1.x); a[1].y += bf_hi(v1.x); a[1].z += bf_lo(v1.y); a[1].w += bf_hi(v1.y);
        a[2].x += bf_lo(v2.x); a[2].y += bf_hi(v2.x); a[2].z += bf_lo(v2.y); a[2].w += bf_hi(v2.y);
        a[3].x += bf_lo(v3.x); a[3].y += bf_hi(v3.x); a[3].z += bf_lo(v3.y); a[3].w += bf_hi(v3.y);
        a[4].x += bf_lo(v4.x); a[4].y += bf_hi(v4.x); a[4].z += bf_lo(v4.y); a[4].w += bf_hi(v4.y);
        a[5].x += bf_lo(v5.x); a[5].y += bf_hi(v5.x); a[5].z += bf_lo(v5.y); a[5].w += bf_hi(v5.y);
        a[6].x += bf_lo(v6.x); a[6].y += bf_hi(v6.x); a[6].z += bf_lo(v6.y); a[6].w += bf_hi(v6.y);
        a[7].x += bf_lo(v7.x); a[7].y += bf_hi(v7.x); a[7].z += bf_lo(v7.y); a[7].w += bf_hi(v7.y);
    }
    for (; i + 3 < r1; i += 4) {
        int s0 = nbr[i + 0], s1 = nbr[i + 1], s2 = nbr[i + 2], s3 = nbr[i + 3];
        uint2 v0 = hb[(size_t)s0 * CU2 + c];
        uint2 v1 = hb[(size_t)s1 * CU2 + c];
        uint2 v2 = hb[(size_t)s2 * CU2 + c];
        uint2 v3 = hb[(size_t)s3 * CU2 + c];
        a[0].x += bf_lo(v0.x); a[0].y += bf_hi(v0.x); a[0].z += bf_lo(v0.y); a[0].w += bf_hi(v0.y);
        a[1].x += bf_lo(v1.x); a[1].y += bf_hi(v1.x); a[1].z += bf_lo(v1.y); a[1].w += bf_hi(v1.y);
        a[2].x += bf_lo(v2.x); a[2].y += bf_hi(v2.x); a[2].z += bf_lo(v2.y); a[2].w += bf_hi(v2.y);
        a[3].x += bf_lo(v3.x); a[3].y += bf_hi(v3.x); a[3].z += bf_lo(v3.y); a[3].w += bf_hi(v3.y);
    }
    for (; i < r1; ++i) {
        uint2 v = hb[(size_t)nbr[i] * CU2 + c];
        a[0].x += bf_lo(v.x); a[0].y += bf_hi(v.x); a[0].z += bf_lo(v.y); a[0].w += bf_hi(v.y);
    }
    #pragma unroll
    for (int u = 1; u < 8; ++u) {
        a[0].x += a[u].x; a[0].y += a[u].y; a[0].z += a[u].z; a[0].w += a[u].w;
    }
    m4[(size_t)n * CU2 + c] = make_float4(a[0].x * inv, a[0].y * inv,
                                          a[0].z * inv, a[0].w * inv);
}

// ------------------------------------------------------- GEMM device function
// 64-node tile staged in LDS (stride K+2); 8 waves; wave w -> cols [16w,16w+16);
// lane -> node; weights via uniform s_load streams.
// MEAN=false: acc=bias, write raw. MEAN=true: acc=out[] RMW, relu.
// WB=true: also write bf16 mirror of the (relu'd) output.
// NOTE: out may alias hin's region block-locally (stage-then-write, safe).
template <int K, bool MEAN, bool WB>
__device__ __forceinline__ void gemm_tile(const float* __restrict__ hin,
                                          const float* __restrict__ w,
                                          const float* __restrict__ bias,
                                          float* __restrict__ out,
                                          uint2* __restrict__ outb,
                                          int blk, int t, float* ls) {
    constexpr int LS = K + 2;
    constexpr int C4 = K / 4;
    int base = blk * 64;
    int lane = t & 63;
    int wid = __builtin_amdgcn_readfirstlane(t >> 6);
    int j0 = wid * 16;
    int node = base + lane;
    bool valid = node < N_NODES;

    const float4* h4 = (const float4*)hin;
    for (int idx = t; idx < 64 * C4; idx += 512) {
        int r = idx / C4, c4 = idx % C4;
        float4 v = (base + r < N_NODES) ? h4[(size_t)(base + r) * C4 + c4]
                                        : make_float4(0.f, 0.f, 0.f, 0.f);
        float* dp = &ls[r * LS + c4 * 4];
        dp[0] = v.x; dp[1] = v.y; dp[2] = v.z; dp[3] = v.w;
    }
    __syncthreads();

    float acc[16];
    if constexpr (MEAN) {
        const float4* o4 = (const float4*)out;
        #pragma unroll
        for (int jj = 0; jj < 4; ++jj) {
            float4 v = valid ? o4[(size_t)node * 32 + wid * 4 + jj]
                             : make_float4(0.f, 0.f, 0.f, 0.f);
            acc[jj * 4 + 0] = v.x; acc[jj * 4 + 1] = v.y;
            acc[jj * 4 + 2] = v.z; acc[jj * 4 + 3] = v.w;
        }
    } else {
        #pragma unroll
        for (int j = 0; j < 16; ++j) acc[j] = bias[j0 + j];
    }

    const float* lrow = &ls[lane * LS];
    #pragma unroll 4
    for (int k = 0; k < K; ++k) {
        float hv = lrow[k];
        const float* wk = &w[(size_t)k * 128 + j0];
        #pragma unroll
        for (int j = 0; j < 16; ++j) acc[j] = fmaf(hv, wk[j], acc[j]);
    }

    if (!valid) return;
    float4* o4 = (float4*)out;
    #pragma unroll
    for (int jj = 0; jj < 4; ++jj) {
        float4 v;
        if constexpr (MEAN) {
            v.x = fmaxf(acc[jj * 4 + 0], 0.f);
            v.y = fmaxf(acc[jj * 4 + 1], 0.f);
            v.z = fmaxf(acc[jj * 4 + 2], 0.f);
            v.w = fmaxf(acc[jj * 4 + 3], 0.f);
        } else {
            v.x = acc[jj * 4 + 0]; v.y = acc[jj * 4 + 1];
            v.z = acc[jj * 4 + 2]; v.w = acc[jj * 4 + 3];
        }
        o4[(size_t)node * 32 + wid * 4 + jj] = v;
        if constexpr (WB) {
            uint2 u; u.x = packbf(v.x, v.y); u.y = packbf(v.z, v.w);
            outb[(size_t)node * 32 + wid * 4 + jj] = u;
        }
    }
}

// ------------------------------------------------- fused agg ∥ selfGEMM layers
__global__ __launch_bounds__(512) void k_fuse1(
    const float* __restrict__ h0, const uint2* __restrict__ h0b,
    const int* __restrict__ rowptr, const int* __restrict__ nbr,
    float* __restrict__ mean1, const float* __restrict__ w1r,
    const float* __restrict__ b1, float* __restrict__ h1) {
    __shared__ float ls[64 * (64 + 2)];
    int b = blockIdx.x;
    if (b % 3 == 2)
        gemm_tile<64, false, false>(h0, w1r, b1, h1, nullptr, b / 3, threadIdx.x, ls);
    else
        agg_tile_bf<64>(h0b, rowptr, nbr, mean1, (b / 3) * 2 + b % 3, threadIdx.x);
}

__global__ __launch_bounds__(512) void k_fuse2(
    const float* __restrict__ h1, const uint2* __restrict__ h1b,
    const int* __restrict__ rowptr, const int* __restrict__ nbr,
    float* __restrict__ mean2, const float* __restrict__ w2r,
    const float* __restrict__ b2, float* __restrict__ h2) {
    __shared__ float ls[64 * (128 + 2)];
    int b = blockIdx.x;
    if (b % 5 == 4)
        gemm_tile<128, false, false>(h1, w2r, b2, h2, nullptr, b / 5, threadIdx.x, ls);
    else
        agg_tile_bf<128>(h1b, rowptr, nbr, mean2, (b / 5) * 4 + b % 5, threadIdx.x);
}

// ------------------------------------------------- mean GEMMs (in-place RMW)
__global__ __launch_bounds__(512) void k_gemm_mean64(
    const float* __restrict__ mean1, const float* __restrict__ w1l,
    float* __restrict__ h1, uint2* __restrict__ h1b) {
    __shared__ float ls[64 * (64 + 2)];
    gemm_tile<64, true, true>(mean1, w1l, nullptr, h1, h1b, blockIdx.x, threadIdx.x, ls);
}

__global__ __launch_bounds__(512) void k_gemm_mean128(
    const float* __restrict__ mean2, const float* __restrict__ w2l,
    float* __restrict__ h2) {
    __shared__ float ls[64 * (128 + 2)];
    gemm_tile<128, true, false>(mean2, w2l, nullptr, h2, nullptr, blockIdx.x, threadIdx.x, ls);
}

// ---------------------------------------------------------------- pool + head
__global__ void k_pool_head(const float* __restrict__ h2, const int* __restrict__ batch,
                            const float* __restrict__ w_out, const float* __restrict__ b_out,
                            float* __restrict__ out) {
    int g = blockIdx.x;
    int lo = 0, hi = N_NODES;
    while (lo < hi) { int mid = (lo + hi) >> 1; if (batch[mid] < g) lo = mid + 1; else hi = mid; }
    int s = lo;
    lo = s; hi = N_NODES;
    while (lo < hi) { int mid = (lo + hi) >> 1; if (batch[mid] < g + 1) lo = mid + 1; else hi = mid; }
    int e = lo;

    int f = threadIdx.x & 127, half = threadIdx.x >> 7;
    float acc = 0.0f;
    for (int r = s + half; r < e; r += 2) acc += h2[(size_t)r * 128 + f];
    __shared__ float tmp[256];
    tmp[threadIdx.x] = acc;
    __syncthreads();
    if (half == 0) {
        float p = (tmp[f] + tmp[f + 128]) / (float)max(e - s, 1);
        tmp[f]       = p * w_out[f * 2 + 0];
        tmp[f + 128] = p * w_out[f * 2 + 1];
    }
    __syncthreads();
    for (int str = 64; str > 0; str >>= 1) {
        if (threadIdx.x < str) {
            tmp[threadIdx.x] += tmp[threadIdx.x + str];
            tmp[threadIdx.x + 128] += tmp[threadIdx.x + 128 + str];
        }
        __syncthreads();
    }
    if (threadIdx.x == 0) {
        out[(size_t)g * 2 + 0] = tmp[0] + b_out[0];
        out[(size_t)g * 2 + 1] = tmp[128] + b_out[1];
    }
}

// ---------------------------------------------------------------- launch
extern "C" void kernel_launch(void* const* d_in, const int* in_sizes, int n_in,
                              void* d_out, int out_size, void* d_ws, size_t ws_size,
                              hipStream_t stream) {
    const int*   x      = (const int*)d_in[0];
    const int*   ei     = (const int*)d_in[1];
    const int*   batch  = (const int*)d_in[2];
    const float* emb    = (const float*)d_in[3];
    const float* w1_l   = (const float*)d_in[4];
    const float* b1     = (const float*)d_in[5];
    const float* w1_r   = (const float*)d_in[6];
    const float* w2_l   = (const float*)d_in[7];
    const float* b2     = (const float*)d_in[8];
    const float* w2_r   = (const float*)d_in[9];
    const float* w_out  = (const float*)d_in[10];
    const float* b_out  = (const float*)d_in[11];
    float* out = (float*)d_out;

    // workspace regions (f32 units) — recycled across phases, same total as R6:
    //  A: h0 (N*64)          -> h1b (N*128 bf16, written by meanG64 after h0 dead)
    //  B: mean1 (N*64)       (dead after meanG64)
    //  C: h1 (N*128)         -> h2 in-place (fuse2 selfGEMM stages row-range then
    //                           overwrites same range; per-block disjoint)
    //  D: mean2 (N*128)      ; first half doubles as h0b (bf16 of h0) until fuse1 done
    float* F = (float*)d_ws;
    float* A = F;
    float* B = A + (size_t)N_NODES * 64;
    float* C = B + (size_t)N_NODES * 64;
    float* D = C + (size_t)N_NODES * 128;
    float* h0    = A;
    uint2* h1b   = (uint2*)A;
    float* mean1 = B;
    float* h1    = C;
    float* h2    = C;
    float* mean2 = D;
    uint2* h0b   = (uint2*)D;
    int*   deg   = (int*)(D + (size_t)N_NODES * 128);
    int*   rowptr= deg + N_NODES;                     // N+1
    int*   wp    = rowptr + N_NODES + 1;              // N
    int*   nbr   = wp + N_NODES;                      // E
    int*   bsums = nbr + N_EDGES;                     // 256

    const int NB = (N_NODES + 255) / 256;             // 196
    const int GB = (N_NODES + 63) / 64;               // 782 GEMM blocks

    hipMemsetAsync(deg, 0, (size_t)N_NODES * sizeof(int), stream);

    k_embed_hist<<<(N_EDGES + 255) / 256, 256, 0, stream>>>(x, emb, ei, h0, h0b, deg);
    k_scanA<<<NB, 256, 0, stream>>>(deg, rowptr, bsums);
    k_scanB<<<1, 256, 0, stream>>>(bsums, NB);
    k_scanC<<<NB, 256, 0, stream>>>(rowptr, wp, bsums);
    k_scatter<<<(N_EDGES + 255) / 256, 256, 0, stream>>>(ei, wp, nbr);

    // layer 1: agg64(bf16 gather) ∥ selfGEMM1 interleaved 2:1
    k_fuse1<<<3 * GB, 512, 0, stream>>>(h0, h0b, rowptr, nbr, mean1, w1_r, b1, h1);
    k_gemm_mean64<<<GB, 512, 0, stream>>>(mean1, w1_l, h1, h1b);

    // layer 2: agg128(bf16 gather) ∥ selfGEMM2 interleaved 4:1; h2 overwrites h1
    k_fuse2<<<5 * GB, 512, 0, stream>>>(h1, h1b, rowptr, nbr, mean2, w2_r, b2, h2);
    k_gemm_mean128<<<GB, 512, 0, stream>>>(mean2, w2_l, h2);

    // pool + head
    k_pool_head<<<N_GRAPHS, 256, 0, stream>>>(h2, batch, w_out, b_out, out);

    (void)in_sizes; (void)n_in; (void)out_size; (void)ws_size;
}